// Round 2
// 272.703 us; speedup vs baseline: 1.4065x; 1.4065x over previous
//
#include <hip/hip_runtime.h>

// Problem dims (fixed by setup_inputs)
#define HH 384
#define WW 512
#define NB 4
#define HWP (HH * WW)       // 196608
#define NPIX (NB * HWP)     // 786432
#define SH 96
#define SW 128
#define SHW (SH * SW)

// Row-banded gather parameters
#define MBOUND 40           // |fy| < 40 handled by banded gather; rest -> overflow list
#define BAND 4              // target rows per block
#define NBANDS (HH / BAND)  // 96
#define OV_CAP 65536        // overflow record capacity (expected ~10 used)

// Strict-IEEE f32 bilinear 4x upsample of (10*flow) — bit-identical to the
// passing round-3 version. Do not touch: floor decisions depend on it.
static __device__ __forceinline__ float upsample_flow_f32(const float* __restrict__ f, int y, int x) {
    float sx = __fadd_rn(__fmul_rn((float)x, 0.25f), -0.375f);  // exact
    float sy = __fadd_rn(__fmul_rn((float)y, 0.25f), -0.375f);  // exact
    float fx0 = floorf(sx), fy0 = floorf(sy);
    float wx = __fsub_rn(sx, fx0);   // exact: {0.625,0.875,0.125,0.375}
    float wy = __fsub_rn(sy, fy0);
    int ix = (int)fx0, iy = (int)fy0;
    int x0 = max(ix, 0), x1 = min(ix + 1, SW - 1);
    int y0 = max(iy, 0), y1 = min(iy + 1, SH - 1);
    float v00 = __fmul_rn(10.0f, f[y0 * SW + x0]);
    float v01 = __fmul_rn(10.0f, f[y0 * SW + x1]);
    float v10 = __fmul_rn(10.0f, f[y1 * SW + x0]);
    float v11 = __fmul_rn(10.0f, f[y1 * SW + x1]);
    float omx = __fsub_rn(1.0f, wx);
    float omy = __fsub_rn(1.0f, wy);
    float w00 = __fmul_rn(omx, omy);
    float w10 = __fmul_rn(wx, omy);
    float w01 = __fmul_rn(omx, wy);
    float w11 = __fmul_rn(wx, wy);
    float s = __fmul_rn(w00, v00);
    s = __fadd_rn(s, __fmul_rn(w10, v01));
    s = __fadd_rn(s, __fmul_rn(w01, v10));
    s = __fadd_rn(s, __fmul_rn(w11, v11));
    return s;
}

// Phase 1: materialize upsampled flow (plain coalesced stores, no atomics).
// Fu layout: [side][comp][b][h][w]  (side stride 2*NPIX, comp stride NPIX).
// Rare |fy|>=MBOUND valid pixels are appended to an exact overflow list living
// in the (currently dead) output buffer: int count @ovf[0], keys @+64 ints,
// vx @+64+OV_CAP floats, vy @+64+2*OV_CAP floats.
__global__ __launch_bounds__(256) void upsample_k(const float* __restrict__ flow01,
                                                  const float* __restrict__ flow10,
                                                  float* __restrict__ Fu, float* __restrict__ ovf) {
    int idx = blockIdx.x * blockDim.x + threadIdx.x;
    if (idx >= NPIX) return;
    int side = blockIdx.y;
    const float* flow = side ? flow10 : flow01;
    int x = idx % WW;
    int y = (idx / WW) % HH;
    int b = idx / HWP;
    const float* fp = flow + b * 2 * SHW;
    float fx = upsample_flow_f32(fp, y, x);
    float fy = upsample_flow_f32(fp + SHW, y, x);
    float* F = Fu + side * 2 * NPIX;
    F[idx] = fx;
    F[NPIX + idx] = fy;
    // overflow detection (exact path for out-of-band rows)
    float x2 = __fadd_rn((float)x, fx);
    float y2 = __fadd_rn((float)y, fy);
    bool valid = (x2 >= 0.0f && x2 <= (float)(WW - 1) && y2 >= 0.0f && y2 <= (float)(HH - 1));
    bool banded = (fy >= -(float)MBOUND && fy < (float)MBOUND);
    if (valid && !banded) {
        int xf = (int)floorf(x2);
        int yf = (int)floorf(y2);
        int key = side * NPIX + b * HWP + yf * WW + xf;
        int slot = atomicAdd((int*)ovf, 1);
        if (slot >= 0 && slot < OV_CAP) {
            ((int*)ovf)[64 + slot] = key;
            ovf[64 + OV_CAP + slot] = -fx;
            ovf[64 + 2 * OV_CAP + slot] = -fy;
        }
    }
}

// Phase 2: one block per (side, b, 4-row target band). Scan the source rows
// that can deposit into this band (|floor(fy)| < MBOUND), accumulate into an
// LDS band histogram with LDS atomics, replay the overflow list, then write
// the completed G rows with plain stores. No global atomics, no G memset.
// blockIdx mapping is XCD-chunked: slab = bid&7 (= side*4+b), band = bid>>3,
// so each XCD owns one contiguous flow slab (1.57 MB, L2-resident).
__global__ __launch_bounds__(256) void row_gather_k(const float* __restrict__ Fu,
                                                    const float* __restrict__ ovf,
                                                    float* __restrict__ g0, float* __restrict__ g1) {
    __shared__ float acc[3][BAND][WW];   // 24 KB
    int bid = blockIdx.x;                // 768 blocks
    int slab = bid & 7;
    int side = slab >> 2;
    int b = slab & 3;
    int t0 = (bid >> 3) * BAND;

    const float* Fx = Fu + side * 2 * NPIX + b * HWP;
    const float* Fyp = Fx + NPIX;

    float* A = &acc[0][0][0];
    for (int k = threadIdx.x; k < 3 * BAND * WW; k += 256) A[k] = 0.0f;
    __syncthreads();

    int sLo = max(t0 - MBOUND, 0);
    int sHi = min(t0 + BAND - 1 + MBOUND, HH - 1);
    for (int s = sLo; s <= sHi; ++s) {
        int rowoff = s * WW + 2 * threadIdx.x;
        float2 fxv = *(const float2*)(Fx + rowoff);
        float2 fyv = *(const float2*)(Fyp + rowoff);
        float sf = (float)s;
        #pragma unroll
        for (int u = 0; u < 2; ++u) {
            int xx = 2 * threadIdx.x + u;
            float fx = u ? fxv.y : fxv.x;
            float fy = u ? fyv.y : fyv.x;
            float x2 = __fadd_rn((float)xx, fx);
            float y2 = __fadd_rn(sf, fy);
            if (x2 >= 0.0f && x2 <= (float)(WW - 1) && y2 >= 0.0f && y2 <= (float)(HH - 1)
                && fy >= -(float)MBOUND && fy < (float)MBOUND) {
                int yf = (int)floorf(y2);
                int r = yf - t0;
                if (r >= 0 && r < BAND) {
                    int xf = (int)floorf(x2);
                    atomicAdd(&acc[0][r][xf], -fx);
                    atomicAdd(&acc[1][r][xf], -fy);
                    atomicAdd(&acc[2][r][xf], 1.0f);
                }
            }
        }
    }

    // replay exact overflow records that land in this band
    int n = ((const int*)ovf)[0];
    n = (n < 0) ? 0 : ((n > OV_CAP) ? OV_CAP : n);
    int lo = t0 * WW, hi = (t0 + BAND) * WW;
    int keybase = side * NPIX + b * HWP;
    for (int i = threadIdx.x; i < n; i += 256) {
        int rel = ((const int*)ovf)[64 + i] - keybase;
        if (rel >= lo && rel < hi) {
            int r = rel / WW - t0;
            int xf = rel % WW;
            atomicAdd(&acc[0][r][xf], ovf[64 + OV_CAP + i]);
            atomicAdd(&acc[1][r][xf], ovf[64 + 2 * OV_CAP + i]);
            atomicAdd(&acc[2][r][xf], 1.0f);
        }
    }
    __syncthreads();

    // write completed G rows: G plane layout [Gx|Gy|Gc], each NPIX
    float* G = (side ? g1 : g0) + b * HWP;
    for (int k = threadIdx.x; k < 3 * BAND * WW; k += 256) {
        int plane = k / (BAND * WW);
        int rem = k % (BAND * WW);
        G[plane * NPIX + t0 * WW + rem] = A[k];
    }
}

// 2x2 weighted box-sum of G == the reference's 4-neighbor scatter result.
// Edge weights: col 0 sees only G(0); col W-1 sees G(W-2) + 2*G(W-1)
// (clipped xf=W-1 deposits twice). Same in y. Weights are exact {1,2,4}.
static __device__ __forceinline__ void box_sum(const float* __restrict__ G, int b, int y, int x,
                                               float& ax, float& ay, float& c) {
    const float* Gx = G;
    const float* Gy = G + NPIX;
    const float* Gc = G + 2 * NPIX;
    float wxs1 = (x == WW - 1) ? 2.0f : 1.0f;
    float wys1 = (y == HH - 1) ? 2.0f : 1.0f;
    float sx = 0.0f, sy = 0.0f, sc = 0.0f;
    int base = b * HWP;
    #pragma unroll
    for (int j = 0; j < 2; j++) {
        int ey = y - 1 + j;
        if (ey < 0) continue;
        float wy = j ? wys1 : 1.0f;
        #pragma unroll
        for (int i = 0; i < 2; i++) {
            int ex = x - 1 + i;
            if (ex < 0) continue;
            float w = wy * ((i ? wxs1 : 1.0f));   // exact
            int o = base + ey * WW + ex;
            sx += w * Gx[o];
            sy += w * Gy[o];
            sc += w * Gc[o];
        }
    }
    ax = sx; ay = sy; c = sc;
}

// Fused box-sum + avg + hole fill, both sides in one dispatch.
// Ft layout = [Ftx | Fty].
__global__ __launch_bounds__(256) void fill2_k(const float* __restrict__ g0, const float* __restrict__ g1,
                                               float* __restrict__ Ft0, float* __restrict__ Ft2) {
    int idx = blockIdx.x * blockDim.x + threadIdx.x;
    if (idx >= NPIX) return;
    int side = blockIdx.y;
    const float* G = side ? g1 : g0;
    float* Ft = side ? Ft2 : Ft0;
    int x = idx % WW;
    int y = (idx / WW) % HH;
    int b = idx / HWP;
    float ax, ay, c;
    box_sum(G, b, y, x, ax, ay, c);
    float ox, oy;
    if (c > 0.0f) {
        ox = ax / c;
        oy = ay / c;
    } else {
        float nx = 0.0f, ny = 0.0f, den = 0.0f;
        float bx, by, bc;
        if (y > 0)      { box_sum(G, b, y - 1, x, bx, by, bc); if (bc > 0.0f) { nx += bx / bc; ny += by / bc; den += 1.0f; } }
        if (y < HH - 1) { box_sum(G, b, y + 1, x, bx, by, bc); if (bc > 0.0f) { nx += bx / bc; ny += by / bc; den += 1.0f; } }
        if (x > 0)      { box_sum(G, b, y, x - 1, bx, by, bc); if (bc > 0.0f) { nx += bx / bc; ny += by / bc; den += 1.0f; } }
        if (x < WW - 1) { box_sum(G, b, y, x + 1, bx, by, bc); if (bc > 0.0f) { nx += bx / bc; ny += by / bc; den += 1.0f; } }
        float inv = 1.0f / fmaxf(den, 1.0f);
        ox = nx * inv;
        oy = ny * inv;
    }
    Ft[idx] = ox;
    Ft[NPIX + idx] = oy;
}

// Filter interpolation, one side per block (blockIdx.z = side*NB + b),
// 1 pixel/thread, 64x4 tile (R6-proven). Interior pixels load each 5-float
// gather row as ONE 20B memcpy (dwordx4+dword) instead of 5 scalar loads:
// 93 -> ~48 VMEM ops per thread in a latency-bound kernel.
__global__ void interp_k(const float* __restrict__ img0, const float* __restrict__ img2,
                         const float* __restrict__ filt0, const float* __restrict__ filt1,
                         const float* __restrict__ Ft0, const float* __restrict__ Ft2,
                         float* __restrict__ out) {
    int x = blockIdx.x * 64 + threadIdx.x;
    int y = blockIdx.y * 4 + threadIdx.y;
    int bz = blockIdx.z;
    int side = bz >> 2;          // NB == 4
    int b = bz & 3;
    const float* img  = side ? img2  : img0;
    const float* filt = side ? filt1 : filt0;
    const float* Ft   = side ? Ft2   : Ft0;

    int idx = b * HWP + y * WW + x;
    float fx = Ft[idx];
    float fy = Ft[NPIX + idx];
    float x2 = fminf(fmaxf((float)x + fx, 0.0f), (float)(WW - 1));
    float y2 = fminf(fmaxf((float)y + fy, 0.0f), (float)(HH - 1));
    float xff = floorf(x2), yff = floorf(y2);
    int xf = (int)xff, yf = (int)yff;
    float a  = x2 - xff;
    float bb = y2 - yff;
    float w00 = (1.0f - a) * (1.0f - bb);
    float w10 = a * (1.0f - bb);
    float w01 = (1.0f - a) * bb;
    float w11 = a * bb;

    // load 4x4 filter taps for this pixel (coalesced per plane)
    float F[4][4];
    #pragma unroll
    for (int k = 0; k < 16; k++) {
        F[k >> 2][k & 3] = filt[((b * 16 + k) * HH + y) * WW + x];
    }
    // fold bilinear weights into a 5x5 effective coefficient map
    float Cf[5][5];
    #pragma unroll
    for (int r = 0; r < 5; r++) {
        #pragma unroll
        for (int sc = 0; sc < 5; sc++) {
            float v = 0.0f;
            if (r < 4 && sc < 4)   v += w00 * F[r][sc];
            if (r < 4 && sc >= 1)  v += w10 * F[r][sc - 1];
            if (r >= 1 && sc < 4)  v += w01 * F[r - 1][sc];
            if (r >= 1 && sc >= 1) v += w11 * F[r - 1][sc - 1];
            Cf[r][sc] = v;
        }
    }
    int rows[5];
    #pragma unroll
    for (int r = 0; r < 5; r++) rows[r] = min(max(yf - 1 + r, 0), HH - 1);

    bool interior = (xf >= 1) && (xf <= WW - 4);
    if (interior) {
        int x0 = xf - 1;   // cols are x0..x0+4, all in-bounds
        #pragma unroll
        for (int c = 0; c < 3; c++) {
            const float* ip = img + (b * 3 + c) * HWP;
            float accv = 0.0f;
            #pragma unroll
            for (int r = 0; r < 5; r++) {
                const float* rp = ip + rows[r] * WW + x0;
                float wrow[5];
                __builtin_memcpy(wrow, rp, 5 * sizeof(float));
                #pragma unroll
                for (int sc = 0; sc < 5; sc++) {
                    accv += Cf[r][sc] * wrow[sc];
                }
            }
            unsafeAtomicAdd(&out[((b * 3 + c) * HH + y) * WW + x], 0.5f * accv);
        }
    } else {
        int cols[5];
        #pragma unroll
        for (int sc = 0; sc < 5; sc++) cols[sc] = min(max(xf - 1 + sc, 0), WW - 1);
        #pragma unroll
        for (int c = 0; c < 3; c++) {
            const float* ip = img + (b * 3 + c) * HWP;
            float accv = 0.0f;
            #pragma unroll
            for (int r = 0; r < 5; r++) {
                const float* rp = ip + rows[r] * WW;
                #pragma unroll
                for (int sc = 0; sc < 5; sc++) {
                    accv += Cf[r][sc] * rp[cols[sc]];
                }
            }
            unsafeAtomicAdd(&out[((b * 3 + c) * HH + y) * WW + x], 0.5f * accv);
        }
    }
}

extern "C" void kernel_launch(void* const* d_in, const int* in_sizes, int n_in,
                              void* d_out, int out_size, void* d_ws, size_t ws_size,
                              hipStream_t stream) {
    const float* input0 = (const float*)d_in[0];
    const float* input2 = (const float*)d_in[1];
    const float* flow01 = (const float*)d_in[2];
    const float* flow10 = (const float*)d_in[3];
    const float* filt0  = (const float*)d_in[4];
    const float* filt1  = (const float*)d_in[5];
    float* out = (float*)d_out;

    float* ws = (float*)d_ws;
    float* g0   = ws;                    // 3*NPIX: Gx, Gy, Gc (side 0)
    float* g1   = ws + 3 * NPIX;         // 3*NPIX (side 1)
    float* Fu   = ws + 6 * NPIX;         // 4*NPIX: upsampled flow [side][comp][...]
    float* Ft0  = ws + 6 * NPIX;         // 2*NPIX (aliases Fu: written by fill2 AFTER
    float* Ft2  = ws + 8 * NPIX;         //         row_gather is done reading Fu)
    float* ovf  = out;                   // overflow counter+records live in dead out buf

    const int BS = 256;
    const int NBLK = (NPIX + BS - 1) / BS;

    // zero overflow counter (first 256 B of out); out itself zeroed AFTER
    // row_gather_k has consumed the overflow list.
    hipMemsetAsync(ovf, 0, 256, stream);

    upsample_k<<<dim3(NBLK, 2), BS, 0, stream>>>(flow01, flow10, Fu, ovf);
    row_gather_k<<<dim3(2 * NB * NBANDS), BS, 0, stream>>>(Fu, ovf, g0, g1);
    hipMemsetAsync(out, 0, (size_t)3 * NPIX * sizeof(float), stream);
    fill2_k<<<dim3(NBLK, 2), BS, 0, stream>>>(g0, g1, Ft0, Ft2);
    interp_k<<<dim3(WW / 64, HH / 4, NB * 2), dim3(64, 4), 0, stream>>>(
        input0, input2, filt0, filt1, Ft0, Ft2, out);
}